// Round 3
// baseline (296.993 us; speedup 1.0000x reference)
//
#include <hip/hip_runtime.h>
#include <hip/hip_bf16.h>

// Problem: B=8, S=1024, EMBED=1024, DK=DV=512, M=64. Inputs/outputs f32.
// Identity: landmark selection is a segment permutation P of k, so
// kernel_1 = K3 P^T, pinv(kernel_2) = P pinv(K3), and
// out = K3 K3+ K3 v = K3 v == softmax(q k^T) v  (standard attention).
#define SS   1024
#define DKK  512

typedef __hip_bfloat16 bf16;
typedef __attribute__((ext_vector_type(8))) short s16x8;            // 8 x bf16
typedef __attribute__((ext_vector_type(8))) unsigned short u16x8;
typedef __attribute__((ext_vector_type(4))) float f32x4;

// ---- ws layout (byte offsets) ----
// W(z) bf16 1 MiB at 48+z MiB; q 52 MiB; k 60 MiB; vT 68 MiB.
#define WS_W(z)  ((48ull << 20) + ((size_t)(z) << 20))
#define WS_Q     (52ull << 20)
#define WS_K     (60ull << 20)
#define WS_VT    (68ull << 20)

__device__ __forceinline__ void async_ld16(const void* g, void* s) {
  __builtin_amdgcn_global_load_lds(
      (const __attribute__((address_space(1))) void*)g,
      (__attribute__((address_space(3))) void*)s, 16, 0, 0);
}

__device__ __forceinline__ unsigned short f2bfu(float f) {
  return __builtin_bit_cast(unsigned short, __float2bfloat16(f));
}
__device__ __forceinline__ float bfu2f(unsigned short u) {
  unsigned int i = ((unsigned int)u) << 16;
  return __builtin_bit_cast(float, i);
}

// Convert the 3 weight tensors (512K elems each) f32 -> bf16 into ws.
__global__ __launch_bounds__(256)
void convert_w(const float* __restrict__ w0, const float* __restrict__ w1,
               const float* __restrict__ w2, char* __restrict__ ws)
{
  const int bx = blockIdx.x;
  const int z = bx >> 8, local = bx & 255;
  const float* src = (z == 0) ? w0 : (z == 1) ? w1 : w2;
  unsigned short* dst = (unsigned short*)(ws + WS_W(z));
  const int i = local * 2048 + threadIdx.x * 8;
  const float4* s = (const float4*)(src + i);
  float4 a = s[0], b = s[1];
  ushort4 o0, o1;
  o0.x = f2bfu(a.x); o0.y = f2bfu(a.y); o0.z = f2bfu(a.z); o0.w = f2bfu(a.w);
  o1.x = f2bfu(b.x); o1.y = f2bfu(b.y); o1.z = f2bfu(b.z); o1.w = f2bfu(b.w);
  ((ushort4*)(dst + i))[0] = o0;
  ((ushort4*)(dst + i))[1] = o1;
}

// ---------- f32-A x bf16-B core for proj: BM=64, BN=256 (round-1 version) ----------
// A f32 staged via reg round-trip + inline cvt into swizzled LDS;
// B bf16 on the async global_load_lds path. Wave tile 32x128.
template<int K, int LDA, int LDB>
__device__ __forceinline__ void gemm_core_f32a(const float* __restrict__ A,
                                               const bf16* __restrict__ Bw,
                                               int bm, int bn,
                                               short* As, short* Bs, f32x4* acc)
{
  const int tid  = threadIdx.x;
  const int lane = tid & 63;
  const int wave = tid >> 6;
  const int l8   = lane >> 3;
  const int kch  = ((lane & 7) ^ l8) * 8;
  const bf16* bg = Bw + (size_t)(bn * 256 + wave * 64 + l8) * LDB + kch;
  short* BsW = Bs + wave * 64 * 64;
  const int arow = tid >> 3;
  const int ag8  = tid & 7;
  const int slotA = (ag8 ^ (arow & 7)) * 8;
  const float* ag = A + (size_t)(bm * 64 + arow) * LDA + ag8 * 8;
  const int waveM = wave >> 1, waveN = wave & 1;
  const int l16  = lane & 15;
  const int quad = lane >> 4;
  const int xr   = l16 & 7;

  #pragma unroll
  for (int t = 0; t < 16; ++t)
    #pragma unroll
    for (int r = 0; r < 4; ++r) acc[t][r] = 0.0f;

  for (int kt = 0; kt < K / 64; ++kt) {
    #pragma unroll
    for (int j = 0; j < 8; ++j) async_ld16(bg + (size_t)j * 8 * LDB, BsW + j * 8 * 64);
    bg += 64;
    #pragma unroll
    for (int p = 0; p < 2; ++p) {
      const float4* s = (const float4*)(ag + (size_t)p * 32 * LDA);
      float4 a = s[0], b = s[1];
      u16x8 v;
      v[0] = f2bfu(a.x); v[1] = f2bfu(a.y); v[2] = f2bfu(a.z); v[3] = f2bfu(a.w);
      v[4] = f2bfu(b.x); v[5] = f2bfu(b.y); v[6] = f2bfu(b.z); v[7] = f2bfu(b.w);
      *(u16x8*)&As[(p * 32 + arow) * 64 + slotA] = v;
    }
    ag += 64;
    __syncthreads();
    #pragma unroll
    for (int ks = 0; ks < 2; ++ks) {
      s16x8 af[2], bfv[8];
      #pragma unroll
      for (int mi = 0; mi < 2; ++mi) {
        const int row  = waveM * 32 + mi * 16 + l16;
        const int slot = (ks * 4 + quad) ^ xr;
        af[mi] = *(const s16x8*)&As[row * 64 + slot * 8];
      }
      #pragma unroll
      for (int ni = 0; ni < 8; ++ni) {
        const int row  = waveN * 128 + ni * 16 + l16;
        const int slot = (ks * 4 + quad) ^ xr;
        bfv[ni] = *(const s16x8*)&Bs[row * 64 + slot * 8];
      }
      #pragma unroll
      for (int mi = 0; mi < 2; ++mi)
        #pragma unroll
        for (int ni = 0; ni < 8; ++ni)
          acc[mi * 8 + ni] = __builtin_amdgcn_mfma_f32_16x16x32_bf16(
              af[mi], bfv[ni], acc[mi * 8 + ni], 0, 0, 0);
    }
    __syncthreads();
  }
}

// z=0: q = (Xq Wq^T + bq) * 512^-0.5 ; z=1: k = Xk Wk^T + bk ;
// z=2: vT[b][d][s] = (Xv Wv^T + bv)^T.
// Flat 768-block grid; the two bn-siblings of each (bm,z) panel get linear
// ids differing by 8 -> same XCD -> A panel shared in that XCD's L2.
__global__ __launch_bounds__(256, 3)
void proj_kernel(const float* __restrict__ Xq, const float* __restrict__ Xk,
                 const float* __restrict__ Xv, const bf16* __restrict__ W0,
                 const float* __restrict__ bq, const float* __restrict__ bk,
                 const float* __restrict__ bv,
                 bf16* __restrict__ qo, bf16* __restrict__ ko,
                 bf16* __restrict__ vT, float qscale)
{
  __shared__ __align__(16) short As[64 * 64];
  __shared__ __align__(16) short Bs[256 * 64];
  const int id   = blockIdx.x;
  const int xcd  = id & 7;
  const int s    = id >> 3;            // 0..95
  const int bn   = s & 1;
  const int pair = (s >> 1) * 8 + xcd; // 0..383 unique
  const int bm   = pair & 127;
  const int z    = pair >> 7;          // 0..2
  const float* A  = (z == 0) ? Xq : (z == 1) ? Xk : Xv;
  const bf16*  Bw = W0 + ((size_t)z << 19);
  const float* bias = (z == 0) ? bq : (z == 1) ? bk : bv;
  f32x4 acc[16];
  gemm_core_f32a<1024, 1024, 1024>(A, Bw, bm, bn, As, Bs, acc);

  const int lane = threadIdx.x & 63;
  const int wave = threadIdx.x >> 6;
  const int waveM = wave >> 1, waveN = wave & 1;
  const int l16 = lane & 15, quad = lane >> 4;
  const int row0 = bm * 64 + waveM * 32;
  const int col0 = bn * 256 + waveN * 128;
  const float sc = (z == 0) ? qscale : 1.0f;
  bf16* C = (z == 0) ? qo : ko;
  #pragma unroll
  for (int ni = 0; ni < 8; ++ni) {
    const int col = col0 + ni * 16 + l16;
    const float bb = bias[col];
    #pragma unroll
    for (int mi = 0; mi < 2; ++mi)
      #pragma unroll
      for (int r = 0; r < 4; ++r) {
        const int row = row0 + mi * 16 + quad * 4 + r;
        const float v = acc[mi * 8 + ni][r] + bb;
        if (z == 2)
          vT[((size_t)(row >> 10) * DKK + col) * SS + (row & (SS - 1))] =
              __float2bfloat16(v);
        else
          C[(size_t)row * DKK + col] = __float2bfloat16(v * sc);
      }
  }
}

// ---------- fused flash attention: out = softmax(q k^T) v ----------
// Grid 256: z = id&7 (head pinned to XCD via id%8), qb = id>>3 (32 q-rows).
// Block = 4 waves. QK^T: wave w computes S cols kv=w*16..+15 (full DK=512
// contraction, q-fragments held in registers, k-fragments direct from L2).
// Online softmax cross-wave via Mt/Lt in LDS; P (32x64 bf16) via LDS.
// PV: wave w owns dv = w*128..+127, v-fragments direct from L2 (vT layout).
__global__ __launch_bounds__(256, 1)
void attn_kernel(const bf16* __restrict__ q, const bf16* __restrict__ kk,
                 const bf16* __restrict__ vT, float* __restrict__ out)
{
  __shared__ __align__(16) short Ps[32 * 64];
  __shared__ __align__(16) float Mt[32 * 4];
  __shared__ __align__(16) float Lt[32 * 4];

  const int id = blockIdx.x;
  const int z  = id & 7;
  const int qb = id >> 3;          // 0..31
  const int tid  = threadIdx.x;
  const int lane = tid & 63;
  const int w    = tid >> 6;       // wave 0..3
  const int l16  = lane & 15;
  const int quad = lane >> 4;

  const bf16* qz = q  + (size_t)z * SS * DKK;
  const bf16* kz = kk + (size_t)z * SS * DKK;
  const bf16* vz = vT + (size_t)z * DKK * SS;

  // ---- q fragments in registers (all 32 rows x 512, per MFMA layout) ----
  s16x8 qf0[16], qf1[16];
  {
    const bf16* q0 = qz + (size_t)(qb * 32 + l16) * DKK + quad * 8;
    const bf16* q1 = q0 + (size_t)16 * DKK;
    #pragma unroll
    for (int ks = 0; ks < 16; ++ks) {
      qf0[ks] = *(const s16x8*)(q0 + ks * 32);
      qf1[ks] = *(const s16x8*)(q1 + ks * 32);
    }
  }

  // per-lane direct-L2 fragment bases
  const bf16* kfl = kz + (size_t)(w * 16 + l16) * DKK + quad * 8;
  const bf16* vfl = vz + (size_t)(w * 128 + l16) * SS + quad * 8;

  f32x4 acc[16];
  #pragma unroll
  for (int t = 0; t < 16; ++t)
    #pragma unroll
    for (int r = 0; r < 4; ++r) acc[t][r] = 0.0f;

  float mrun0[4], mrun1[4], lrun0[4], lrun1[4];
  #pragma unroll
  for (int r = 0; r < 4; ++r) {
    mrun0[r] = -1e30f; mrun1[r] = -1e30f;
    lrun0[r] = 0.0f;   lrun1[r] = 0.0f;
  }

  for (int it = 0; it < 16; ++it) {
    const int kv0 = it * 64;
    // ---- QK^T: S tile 32 x 16 (this wave's cols) ----
    f32x4 s0, s1;
    #pragma unroll
    for (int r = 0; r < 4; ++r) { s0[r] = 0.0f; s1[r] = 0.0f; }
    const bf16* kp = kfl + (size_t)kv0 * DKK;
    #pragma unroll
    for (int ks = 0; ks < 16; ++ks) {
      const s16x8 bfk = *(const s16x8*)(kp + ks * 32);
      s0 = __builtin_amdgcn_mfma_f32_16x16x32_bf16(qf0[ks], bfk, s0, 0, 0, 0);
      s1 = __builtin_amdgcn_mfma_f32_16x16x32_bf16(qf1[ks], bfk, s1, 0, 0, 0);
    }

    // ---- wave-local row-max over this wave's 16 kv cols ----
    float mt0[4], mt1[4];
    #pragma unroll
    for (int r = 0; r < 4; ++r) {
      float v0 = s0[r], v1 = s1[r];
      #pragma unroll
      for (int msk = 1; msk < 16; msk <<= 1) {
        v0 = fmaxf(v0, __shfl_xor(v0, msk));
        v1 = fmaxf(v1, __shfl_xor(v1, msk));
      }
      mt0[r] = v0; mt1[r] = v1;
    }
    if (l16 == 0) {
      #pragma unroll
      for (int r = 0; r < 4; ++r) {
        Mt[(quad * 4 + r) * 4 + w] = mt0[r];
        Mt[(16 + quad * 4 + r) * 4 + w] = mt1[r];
      }
    }
    __syncthreads();   // B1: Mt complete; prev-iter Ps reads complete

    // ---- combine max, alpha, exp; partial sums; write P ----
    float al0[4], al1[4], p0[4], p1[4];
    #pragma unroll
    for (int r = 0; r < 4; ++r) {
      {
        const f32x4 mv = *(const f32x4*)&Mt[(quad * 4 + r) * 4];
        const float mtile = fmaxf(fmaxf(mv[0], mv[1]), fmaxf(mv[2], mv[3]));
        const float mnew = fmaxf(mrun0[r], mtile);
        al0[r] = __expf(mrun0[r] - mnew);
        mrun0[r] = mnew;
        p0[r] = __expf(s0[r] - mnew);
      }
      {
        const f32x4 mv = *(const f32x4*)&Mt[(16 + quad * 4 + r) * 4];
        const float mtile = fmaxf(fmaxf(mv[0], mv[1]), fmaxf(mv[2], mv[3]));
        const float mnew = fmaxf(mrun1[r], mtile);
        al1[r] = __expf(mrun1[r] - mnew);
        mrun1[r] = mnew;
        p1[r] = __expf(s1[r] - mnew);
      }
    }
    // row-sum of p over the 16 cols
    #pragma unroll
    for (int r = 0; r < 4; ++r) {
      float e0 = p0[r], e1 = p1[r];
      #pragma unroll
      for (int msk = 1; msk < 16; msk <<= 1) {
        e0 += __shfl_xor(e0, msk);
        e1 += __shfl_xor(e1, msk);
      }
      if (l16 == 0) {
        Lt[(quad * 4 + r) * 4 + w] = e0;
        Lt[(16 + quad * 4 + r) * 4 + w] = e1;
      }
    }
    // write P (bf16) into swizzled LDS tile: slot8 ^= (row>>1)&7
    {
      const int colP = w * 16 + l16;
      const int c8 = colP >> 3, cb = colP & 7;
      #pragma unroll
      for (int r = 0; r < 4; ++r) {
        {
          const int row = quad * 4 + r;
          Ps[row * 64 + ((c8 ^ ((row >> 1) & 7)) * 8) + cb] = (short)f2bfu(p0[r]);
        }
        {
          const int row = 16 + quad * 4 + r;
          Ps[row * 64 + ((c8 ^ ((row >> 1) & 7)) * 8) + cb] = (short)f2bfu(p1[r]);
        }
      }
    }
    __syncthreads();   // B2: Ps/Lt complete

    // ---- l update + O rescale ----
    #pragma unroll
    for (int r = 0; r < 4; ++r) {
      {
        const f32x4 lv = *(const f32x4*)&Lt[(quad * 4 + r) * 4];
        lrun0[r] = lrun0[r] * al0[r] + (lv[0] + lv[1] + lv[2] + lv[3]);
      }
      {
        const f32x4 lv = *(const f32x4*)&Lt[(16 + quad * 4 + r) * 4];
        lrun1[r] = lrun1[r] * al1[r] + (lv[0] + lv[1] + lv[2] + lv[3]);
      }
    }
    #pragma unroll
    for (int ni = 0; ni < 8; ++ni)
      #pragma unroll
      for (int r = 0; r < 4; ++r) {
        acc[ni][r]     *= al0[r];
        acc[8 + ni][r] *= al1[r];
      }

    // ---- PV: O[32 x 128(w)] += P(32x64) . vT-slice ----
    const bf16* vp = vfl + kv0;
    #pragma unroll
    for (int ks = 0; ks < 2; ++ks) {
      s16x8 pa0, pa1;
      {
        const int row = l16;
        const int sl = (ks * 4 + quad) ^ ((row >> 1) & 7);
        pa0 = *(const s16x8*)&Ps[row * 64 + sl * 8];
      }
      {
        const int row = 16 + l16;
        const int sl = (ks * 4 + quad) ^ ((row >> 1) & 7);
        pa1 = *(const s16x8*)&Ps[row * 64 + sl * 8];
      }
      #pragma unroll
      for (int ni = 0; ni < 8; ++ni) {
        const s16x8 vf = *(const s16x8*)(vp + (size_t)ni * 16 * SS + ks * 32);
        acc[ni]     = __builtin_amdgcn_mfma_f32_16x16x32_bf16(pa0, vf, acc[ni], 0, 0, 0);
        acc[8 + ni] = __builtin_amdgcn_mfma_f32_16x16x32_bf16(pa1, vf, acc[8 + ni], 0, 0, 0);
      }
    }
  }

  // ---- epilogue: normalize and write f32 ----
  float* oz = out + (size_t)z * SS * DKK;
  #pragma unroll
  for (int r = 0; r < 4; ++r) {
    const float i0 = 1.0f / lrun0[r];
    const float i1 = 1.0f / lrun1[r];
    #pragma unroll
    for (int ni = 0; ni < 8; ++ni) {
      const int col = w * 128 + ni * 16 + l16;
      oz[(size_t)(qb * 32 + quad * 4 + r) * DKK + col]      = acc[ni][r] * i0;
      oz[(size_t)(qb * 32 + 16 + quad * 4 + r) * DKK + col] = acc[8 + ni][r] * i1;
    }
  }
}

extern "C" void kernel_launch(void* const* d_in, const int* in_sizes, int n_in,
                              void* d_out, int out_size, void* d_ws, size_t ws_size,
                              hipStream_t stream)
{
  char* ws = (char*)d_ws;
  bf16*  W0   = (bf16*)(ws + WS_W(0));
  bf16*  q    = (bf16*)(ws + WS_Q);
  bf16*  kk   = (bf16*)(ws + WS_K);
  bf16*  vT   = (bf16*)(ws + WS_VT);

  const float qscale = 0.044194173824159216f;  // 512^-0.5

  dim3 blk(256, 1, 1);
  // d_in order: qin,kin,vin,Wq,bq,Wk,bk,Wv,bv (all f32)
  hipLaunchKernelGGL(convert_w, dim3(768), blk, 0, stream,
                     (const float*)d_in[3], (const float*)d_in[5],
                     (const float*)d_in[7], ws);
  hipLaunchKernelGGL(proj_kernel, dim3(768, 1, 1), blk, 0, stream,
                     (const float*)d_in[0], (const float*)d_in[1],
                     (const float*)d_in[2], W0,
                     (const float*)d_in[4], (const float*)d_in[6],
                     (const float*)d_in[8], q, kk, vT, qscale);
  hipLaunchKernelGGL(attn_kernel, dim3(256, 1, 1), blk, 0, stream,
                     q, kk, vT, (float*)d_out);
}

// Round 4
// 217.924 us; speedup vs baseline: 1.3628x; 1.3628x over previous
//
#include <hip/hip_runtime.h>
#include <hip/hip_bf16.h>

// Problem: B=8, S=1024, EMBED=1024, DK=DV=512, M=64. Inputs/outputs f32.
// Identity: landmark selection is a segment permutation P of k, so
// kernel_1 = K3 P^T, pinv(kernel_2) = P pinv(K3), and
// out = K3 K3+ K3 v = K3 v == softmax(q k^T) v  (standard attention).
#define SS   1024
#define DKK  512

typedef __hip_bfloat16 bf16;
typedef __attribute__((ext_vector_type(8))) short s16x8;            // 8 x bf16
typedef __attribute__((ext_vector_type(8))) unsigned short u16x8;
typedef __attribute__((ext_vector_type(4))) float f32x4;

// ---- ws layout (byte offsets) ----
// logits/P 16 MiB at 0; W(z) bf16 1 MiB at 48+z MiB; q 52 MiB; k 60 MiB;
// vT 68 MiB.
#define WS_W(z)  ((48ull << 20) + ((size_t)(z) << 20))
#define WS_Q     (52ull << 20)
#define WS_K     (60ull << 20)
#define WS_VT    (68ull << 20)
#define WS_LG    (0ull)

__device__ __forceinline__ void async_ld16(const void* g, void* s) {
  __builtin_amdgcn_global_load_lds(
      (const __attribute__((address_space(1))) void*)g,
      (__attribute__((address_space(3))) void*)s, 16, 0, 0);
}

__device__ __forceinline__ unsigned short f2bfu(float f) {
  return __builtin_bit_cast(unsigned short, __float2bfloat16(f));
}
__device__ __forceinline__ float bfu2f(unsigned short u) {
  unsigned int i = ((unsigned int)u) << 16;
  return __builtin_bit_cast(float, i);
}

// Convert the 3 weight tensors (512K elems each) f32 -> bf16 into ws.
__global__ __launch_bounds__(256)
void convert_w(const float* __restrict__ w0, const float* __restrict__ w1,
               const float* __restrict__ w2, char* __restrict__ ws)
{
  const int bx = blockIdx.x;
  const int z = bx >> 8, local = bx & 255;
  const float* src = (z == 0) ? w0 : (z == 1) ? w1 : w2;
  unsigned short* dst = (unsigned short*)(ws + WS_W(z));
  const int i = local * 2048 + threadIdx.x * 8;
  const float4* s = (const float4*)(src + i);
  float4 a = s[0], b = s[1];
  ushort4 o0, o1;
  o0.x = f2bfu(a.x); o0.y = f2bfu(a.y); o0.z = f2bfu(a.z); o0.w = f2bfu(a.w);
  o1.x = f2bfu(b.x); o1.y = f2bfu(b.y); o1.z = f2bfu(b.z); o1.w = f2bfu(b.w);
  ((ushort4*)(dst + i))[0] = o0;
  ((ushort4*)(dst + i))[1] = o1;
}

// ---------- bf16 x bf16 core ----------
// C[BM x 128] = A[BM x K] * B[128 x K]^T, both K-contiguous bf16.
// LDS via global_load_lds w=16; LDS[row][slot] holds chunk (slot ^ (row&7)).
// 4 waves, wave tile (BM/2) x 64, acc[mi*4+ni] with MI = BM/32.
template<int BM, int K, int LDA, int LDB>
__device__ __forceinline__ void gemm_core(const bf16* __restrict__ A,
                                          const bf16* __restrict__ Bw,
                                          int bm, int bn,
                                          short* As, short* Bs, f32x4* acc)
{
  constexpr int MI = BM / 32;
  constexpr int AR = BM / 4;
  const int tid  = threadIdx.x;
  const int lane = tid & 63;
  const int wave = tid >> 6;
  const int l8   = lane >> 3;
  const int kch  = ((lane & 7) ^ l8) * 8;
  const bf16* ag = A  + (size_t)(bm * BM + wave * AR + l8) * LDA + kch;
  const bf16* bg = Bw + (size_t)(bn * 128 + wave * 32 + l8) * LDB + kch;
  short* AsW = As + wave * AR * 64;
  short* BsW = Bs + wave * 32 * 64;
  const int waveM = wave >> 1, waveN = wave & 1;
  const int l16  = lane & 15;
  const int quad = lane >> 4;
  const int xr   = l16 & 7;

  #pragma unroll
  for (int t = 0; t < MI * 4; ++t)
    #pragma unroll
    for (int r = 0; r < 4; ++r) acc[t][r] = 0.0f;

  for (int kt = 0; kt < K / 64; ++kt) {
    #pragma unroll
    for (int j = 0; j < AR / 8; ++j) async_ld16(ag + (size_t)j * 8 * LDA, AsW + j * 8 * 64);
    #pragma unroll
    for (int j = 0; j < 4; ++j)      async_ld16(bg + (size_t)j * 8 * LDB, BsW + j * 8 * 64);
    ag += 64; bg += 64;
    __syncthreads();
    #pragma unroll
    for (int ks = 0; ks < 2; ++ks) {
      s16x8 af[MI], bfv[4];
      #pragma unroll
      for (int mi = 0; mi < MI; ++mi) {
        const int row  = waveM * (BM / 2) + mi * 16 + l16;
        const int slot = (ks * 4 + quad) ^ xr;
        af[mi] = *(const s16x8*)&As[row * 64 + slot * 8];
      }
      #pragma unroll
      for (int ni = 0; ni < 4; ++ni) {
        const int row  = waveN * 64 + ni * 16 + l16;
        const int slot = (ks * 4 + quad) ^ xr;
        bfv[ni] = *(const s16x8*)&Bs[row * 64 + slot * 8];
      }
      #pragma unroll
      for (int mi = 0; mi < MI; ++mi)
        #pragma unroll
        for (int ni = 0; ni < 4; ++ni)
          acc[mi * 4 + ni] = __builtin_amdgcn_mfma_f32_16x16x32_bf16(
              af[mi], bfv[ni], acc[mi * 4 + ni], 0, 0, 0);
    }
    __syncthreads();
  }
}

// ---------- f32-A x bf16-B core for proj: BM=64, BN=256 (round-1 version) ----------
// A f32 staged via reg round-trip + inline cvt into swizzled LDS;
// B bf16 on the async global_load_lds path. Wave tile 32x128.
template<int K, int LDA, int LDB>
__device__ __forceinline__ void gemm_core_f32a(const float* __restrict__ A,
                                               const bf16* __restrict__ Bw,
                                               int bm, int bn,
                                               short* As, short* Bs, f32x4* acc)
{
  const int tid  = threadIdx.x;
  const int lane = tid & 63;
  const int wave = tid >> 6;
  const int l8   = lane >> 3;
  const int kch  = ((lane & 7) ^ l8) * 8;
  const bf16* bg = Bw + (size_t)(bn * 256 + wave * 64 + l8) * LDB + kch;
  short* BsW = Bs + wave * 64 * 64;
  const int arow = tid >> 3;
  const int ag8  = tid & 7;
  const int slotA = (ag8 ^ (arow & 7)) * 8;
  const float* ag = A + (size_t)(bm * 64 + arow) * LDA + ag8 * 8;
  const int waveM = wave >> 1, waveN = wave & 1;
  const int l16  = lane & 15;
  const int quad = lane >> 4;
  const int xr   = l16 & 7;

  #pragma unroll
  for (int t = 0; t < 16; ++t)
    #pragma unroll
    for (int r = 0; r < 4; ++r) acc[t][r] = 0.0f;

  for (int kt = 0; kt < K / 64; ++kt) {
    #pragma unroll
    for (int j = 0; j < 8; ++j) async_ld16(bg + (size_t)j * 8 * LDB, BsW + j * 8 * 64);
    bg += 64;
    #pragma unroll
    for (int p = 0; p < 2; ++p) {
      const float4* s = (const float4*)(ag + (size_t)p * 32 * LDA);
      float4 a = s[0], b = s[1];
      u16x8 v;
      v[0] = f2bfu(a.x); v[1] = f2bfu(a.y); v[2] = f2bfu(a.z); v[3] = f2bfu(a.w);
      v[4] = f2bfu(b.x); v[5] = f2bfu(b.y); v[6] = f2bfu(b.z); v[7] = f2bfu(b.w);
      *(u16x8*)&As[(p * 32 + arow) * 64 + slotA] = v;
    }
    ag += 64;
    __syncthreads();
    #pragma unroll
    for (int ks = 0; ks < 2; ++ks) {
      s16x8 af[2], bfv[8];
      #pragma unroll
      for (int mi = 0; mi < 2; ++mi) {
        const int row  = waveM * 32 + mi * 16 + l16;
        const int slot = (ks * 4 + quad) ^ xr;
        af[mi] = *(const s16x8*)&As[row * 64 + slot * 8];
      }
      #pragma unroll
      for (int ni = 0; ni < 8; ++ni) {
        const int row  = waveN * 128 + ni * 16 + l16;
        const int slot = (ks * 4 + quad) ^ xr;
        bfv[ni] = *(const s16x8*)&Bs[row * 64 + slot * 8];
      }
      #pragma unroll
      for (int mi = 0; mi < 2; ++mi)
        #pragma unroll
        for (int ni = 0; ni < 8; ++ni)
          acc[mi * 8 + ni] = __builtin_amdgcn_mfma_f32_16x16x32_bf16(
              af[mi], bfv[ni], acc[mi * 8 + ni], 0, 0, 0);
    }
    __syncthreads();
  }
}

// z=0: q = (Xq Wq^T + bq) * 512^-0.5 ; z=1: k = Xk Wk^T + bk ;
// z=2: vT[b][d][s] = (Xv Wv^T + bv)^T.
// Flat 768-block grid; the two bn-siblings of each (bm,z) panel get linear
// ids differing by 8 -> same XCD -> A panel shared in that XCD's L2.
__global__ __launch_bounds__(256, 3)
void proj_kernel(const float* __restrict__ Xq, const float* __restrict__ Xk,
                 const float* __restrict__ Xv, const bf16* __restrict__ W0,
                 const float* __restrict__ bq, const float* __restrict__ bk,
                 const float* __restrict__ bv,
                 bf16* __restrict__ qo, bf16* __restrict__ ko,
                 bf16* __restrict__ vT, float qscale)
{
  __shared__ __align__(16) short As[64 * 64];
  __shared__ __align__(16) short Bs[256 * 64];
  const int id   = blockIdx.x;
  const int xcd  = id & 7;
  const int s    = id >> 3;            // 0..95
  const int bn   = s & 1;
  const int pair = (s >> 1) * 8 + xcd; // 0..383 unique
  const int bm   = pair & 127;
  const int z    = pair >> 7;          // 0..2
  const float* A  = (z == 0) ? Xq : (z == 1) ? Xk : Xv;
  const bf16*  Bw = W0 + ((size_t)z << 19);
  const float* bias = (z == 0) ? bq : (z == 1) ? bk : bv;
  f32x4 acc[16];
  gemm_core_f32a<1024, 1024, 1024>(A, Bw, bm, bn, As, Bs, acc);

  const int lane = threadIdx.x & 63;
  const int wave = threadIdx.x >> 6;
  const int waveM = wave >> 1, waveN = wave & 1;
  const int l16 = lane & 15, quad = lane >> 4;
  const int row0 = bm * 64 + waveM * 32;
  const int col0 = bn * 256 + waveN * 128;
  const float sc = (z == 0) ? qscale : 1.0f;
  bf16* C = (z == 0) ? qo : ko;
  #pragma unroll
  for (int ni = 0; ni < 8; ++ni) {
    const int col = col0 + ni * 16 + l16;
    const float bb = bias[col];
    #pragma unroll
    for (int mi = 0; mi < 2; ++mi)
      #pragma unroll
      for (int r = 0; r < 4; ++r) {
        const int row = row0 + mi * 16 + quad * 4 + r;
        const float v = acc[mi * 8 + ni][r] + bb;
        if (z == 2)
          vT[((size_t)(row >> 10) * DKK + col) * SS + (row & (SS - 1))] =
              __float2bfloat16(v);
        else
          C[(size_t)row * DKK + col] = __float2bfloat16(v * sc);
      }
  }
}

// logits[b][s][t] = q[b][s].k[b][t]; 128x128 tiles, pure GEMM + store.
// Flat grid 512: z = id&7 (head pinned to its XCD; q+k for one z = 2 MiB,
// L2-resident), s = id>>3: bm = s&7, bn = s>>3.
__global__ __launch_bounds__(256, 2)
void scores_kernel(const bf16* __restrict__ q, const bf16* __restrict__ k,
                   bf16* __restrict__ lgB)
{
  __shared__ __align__(16) short As[128 * 64];
  __shared__ __align__(16) short Bs[128 * 64];
  const int id = blockIdx.x;
  const int z  = id & 7;
  const int s  = id >> 3;          // 0..63
  const int bm = s & 7;
  const int bn = s >> 3;           // 0..7
  f32x4 acc[16];
  gemm_core<128, 512, 512, 512>(q + (size_t)z * SS * DKK, k + (size_t)z * SS * DKK,
                                bm, bn, As, Bs, acc);

  const int lane = threadIdx.x & 63;
  const int wave = threadIdx.x >> 6;
  const int waveM = wave >> 1, waveN = wave & 1;
  const int l16 = lane & 15, quad = lane >> 4;
  const int row0 = bm * 128 + waveM * 64;
  const int col0 = bn * 128 + waveN * 64;
  bf16* C = lgB + (size_t)z * SS * SS;
  #pragma unroll
  for (int ni = 0; ni < 4; ++ni) {
    const int col = col0 + ni * 16 + l16;
    #pragma unroll
    for (int mi = 0; mi < 4; ++mi)
      #pragma unroll
      for (int r = 0; r < 4; ++r) {
        const int row = row0 + mi * 16 + quad * 4 + r;
        C[(size_t)row * SS + col] = __float2bfloat16(acc[mi * 4 + ni][r]);
      }
  }
}

// In-place row softmax over the bf16 logits: P = exp(x - max) / sum.
// One wave per row (1024 cols = 16 bf16/lane). Flat grid 2048:
// z = id&7, rb = id>>3 (4 rows per block, one per wave).
__global__ __launch_bounds__(256)
void softmax_p(unsigned short* __restrict__ lg)
{
  const int id = blockIdx.x;
  const int z  = id & 7;
  const int rb = id >> 3;               // 0..255
  const int w    = threadIdx.x >> 6;
  const int lane = threadIdx.x & 63;
  const int row  = rb * 4 + w;
  unsigned short* p = lg + ((size_t)z * SS + row) * SS + lane * 16;

  u16x8 a = *(const u16x8*)p;
  u16x8 b = *(const u16x8*)(p + 8);
  float xf[16];
  #pragma unroll
  for (int j = 0; j < 8; ++j) { xf[j] = bfu2f(a[j]); xf[8 + j] = bfu2f(b[j]); }

  float m = xf[0];
  #pragma unroll
  for (int j = 1; j < 16; ++j) m = fmaxf(m, xf[j]);
  #pragma unroll
  for (int msk = 1; msk < 64; msk <<= 1) m = fmaxf(m, __shfl_xor(m, msk));

  float e[16];
  float L = 0.f;
  #pragma unroll
  for (int j = 0; j < 16; ++j) { e[j] = __expf(xf[j] - m); L += e[j]; }
  #pragma unroll
  for (int msk = 1; msk < 64; msk <<= 1) L += __shfl_xor(L, msk);
  const float R = 1.0f / L;

  u16x8 o0, o1;
  #pragma unroll
  for (int j = 0; j < 8; ++j) {
    o0[j] = f2bfu(e[j] * R);
    o1[j] = f2bfu(e[8 + j] * R);
  }
  *(u16x8*)p = o0;
  *(u16x8*)(p + 8) = o1;
}

// out[b][s][d] = P[b][s][:] . vT[b][d][:]; pure bf16 GEMM, f32 out.
// Flat grid 256: z = id&7 (P slab 2 MiB + vT 1 MiB per z, L2-resident),
// s = id>>3: bm = s&7, bn = s>>3 (0..3).
__global__ __launch_bounds__(256, 2)
void pv_kernel(const bf16* __restrict__ P, const bf16* __restrict__ vT,
               float* __restrict__ out)
{
  __shared__ __align__(16) short As[128 * 64];
  __shared__ __align__(16) short Bs[128 * 64];
  const int id = blockIdx.x;
  const int z  = id & 7;
  const int s  = id >> 3;          // 0..31
  const int bm = s & 7;
  const int bn = s >> 3;           // 0..3
  f32x4 acc[16];
  gemm_core<128, 1024, 1024, 1024>(P + (size_t)z * SS * SS,
                                   vT + (size_t)z * DKK * SS,
                                   bm, bn, As, Bs, acc);

  const int lane = threadIdx.x & 63;
  const int wave = threadIdx.x >> 6;
  const int waveM = wave >> 1, waveN = wave & 1;
  const int l16 = lane & 15, quad = lane >> 4;
  const int row0 = bm * 128 + waveM * 64;
  const int col0 = bn * 128 + waveN * 64;
  float* C = out + (size_t)z * SS * DKK;
  #pragma unroll
  for (int ni = 0; ni < 4; ++ni) {
    const int col = col0 + ni * 16 + l16;
    #pragma unroll
    for (int mi = 0; mi < 4; ++mi)
      #pragma unroll
      for (int r = 0; r < 4; ++r) {
        const int row = row0 + mi * 16 + quad * 4 + r;
        C[(size_t)row * DKK + col] = acc[mi * 4 + ni][r];
      }
  }
}

extern "C" void kernel_launch(void* const* d_in, const int* in_sizes, int n_in,
                              void* d_out, int out_size, void* d_ws, size_t ws_size,
                              hipStream_t stream)
{
  char* ws = (char*)d_ws;
  bf16*  W0   = (bf16*)(ws + WS_W(0));
  bf16*  q    = (bf16*)(ws + WS_Q);
  bf16*  kk   = (bf16*)(ws + WS_K);
  bf16*  vT   = (bf16*)(ws + WS_VT);
  bf16*  lgB  = (bf16*)(ws + WS_LG);

  const float qscale = 0.044194173824159216f;  // 512^-0.5

  dim3 blk(256, 1, 1);
  // d_in order: qin,kin,vin,Wq,bq,Wk,bk,Wv,bv (all f32)
  hipLaunchKernelGGL(convert_w, dim3(768), blk, 0, stream,
                     (const float*)d_in[3], (const float*)d_in[5],
                     (const float*)d_in[7], ws);
  hipLaunchKernelGGL(proj_kernel, dim3(768, 1, 1), blk, 0, stream,
                     (const float*)d_in[0], (const float*)d_in[1],
                     (const float*)d_in[2], W0,
                     (const float*)d_in[4], (const float*)d_in[6],
                     (const float*)d_in[8], q, kk, vT, qscale);
  hipLaunchKernelGGL(scores_kernel, dim3(512, 1, 1), blk, 0, stream,
                     q, kk, lgB);
  hipLaunchKernelGGL(softmax_p, dim3(2048, 1, 1), blk, 0, stream,
                     (unsigned short*)lgB);
  hipLaunchKernelGGL(pv_kernel, dim3(256, 1, 1), blk, 0, stream,
                     lgB, vT, (float*)d_out);
}

// Round 5
// 210.064 us; speedup vs baseline: 1.4138x; 1.0374x over previous
//
#include <hip/hip_runtime.h>
#include <hip/hip_bf16.h>

// Problem: B=8, S=1024, EMBED=1024, DK=DV=512, M=64. Inputs/outputs f32.
// Identity: landmark selection is a segment permutation P of k, so
// kernel_1 = K3 P^T, pinv(kernel_2) = P pinv(K3), and
// out = K3 K3+ K3 v = K3 v == softmax(q k^T) v  (standard attention).
#define SS   1024
#define DKK  512

typedef __hip_bfloat16 bf16;
typedef __attribute__((ext_vector_type(8))) short s16x8;            // 8 x bf16
typedef __attribute__((ext_vector_type(8))) unsigned short u16x8;
typedef __attribute__((ext_vector_type(4))) float f32x4;

// ---- ws layout (byte offsets) ----
// logits/P 16 MiB at 0; W(z) bf16 1 MiB at 48+z MiB; q 52 MiB; k 60 MiB;
// vT 68 MiB.
#define WS_W(z)  ((48ull << 20) + ((size_t)(z) << 20))
#define WS_Q     (52ull << 20)
#define WS_K     (60ull << 20)
#define WS_VT    (68ull << 20)
#define WS_LG    (0ull)

__device__ __forceinline__ void async_ld16(const void* g, void* s) {
  __builtin_amdgcn_global_load_lds(
      (const __attribute__((address_space(1))) void*)g,
      (__attribute__((address_space(3))) void*)s, 16, 0, 0);
}

__device__ __forceinline__ unsigned short f2bfu(float f) {
  return __builtin_bit_cast(unsigned short, __float2bfloat16(f));
}
__device__ __forceinline__ float bfu2f(unsigned short u) {
  unsigned int i = ((unsigned int)u) << 16;
  return __builtin_bit_cast(float, i);
}

// Convert the 3 weight tensors (512K elems each) f32 -> bf16 into ws.
__global__ __launch_bounds__(256)
void convert_w(const float* __restrict__ w0, const float* __restrict__ w1,
               const float* __restrict__ w2, char* __restrict__ ws)
{
  const int bx = blockIdx.x;
  const int z = bx >> 8, local = bx & 255;
  const float* src = (z == 0) ? w0 : (z == 1) ? w1 : w2;
  unsigned short* dst = (unsigned short*)(ws + WS_W(z));
  const int i = local * 2048 + threadIdx.x * 8;
  const float4* s = (const float4*)(src + i);
  float4 a = s[0], b = s[1];
  ushort4 o0, o1;
  o0.x = f2bfu(a.x); o0.y = f2bfu(a.y); o0.z = f2bfu(a.z); o0.w = f2bfu(a.w);
  o1.x = f2bfu(b.x); o1.y = f2bfu(b.y); o1.z = f2bfu(b.z); o1.w = f2bfu(b.w);
  ((ushort4*)(dst + i))[0] = o0;
  ((ushort4*)(dst + i))[1] = o1;
}

// ---------- bf16 x bf16 core ----------
// C[BM x 128] = A[BM x K] * B[128 x K]^T, both K-contiguous bf16.
// LDS via global_load_lds w=16; LDS[row][slot] holds chunk (slot ^ (row&7)).
// 4 waves, wave tile (BM/2) x 64, acc[mi*4+ni] with MI = BM/32.
template<int BM, int K, int LDA, int LDB>
__device__ __forceinline__ void gemm_core(const bf16* __restrict__ A,
                                          const bf16* __restrict__ Bw,
                                          int bm, int bn,
                                          short* As, short* Bs, f32x4* acc)
{
  constexpr int MI = BM / 32;
  constexpr int AR = BM / 4;
  const int tid  = threadIdx.x;
  const int lane = tid & 63;
  const int wave = tid >> 6;
  const int l8   = lane >> 3;
  const int kch  = ((lane & 7) ^ l8) * 8;
  const bf16* ag = A  + (size_t)(bm * BM + wave * AR + l8) * LDA + kch;
  const bf16* bg = Bw + (size_t)(bn * 128 + wave * 32 + l8) * LDB + kch;
  short* AsW = As + wave * AR * 64;
  short* BsW = Bs + wave * 32 * 64;
  const int waveM = wave >> 1, waveN = wave & 1;
  const int l16  = lane & 15;
  const int quad = lane >> 4;
  const int xr   = l16 & 7;

  #pragma unroll
  for (int t = 0; t < MI * 4; ++t)
    #pragma unroll
    for (int r = 0; r < 4; ++r) acc[t][r] = 0.0f;

  for (int kt = 0; kt < K / 64; ++kt) {
    #pragma unroll
    for (int j = 0; j < AR / 8; ++j) async_ld16(ag + (size_t)j * 8 * LDA, AsW + j * 8 * 64);
    #pragma unroll
    for (int j = 0; j < 4; ++j)      async_ld16(bg + (size_t)j * 8 * LDB, BsW + j * 8 * 64);
    ag += 64; bg += 64;
    __syncthreads();
    #pragma unroll
    for (int ks = 0; ks < 2; ++ks) {
      s16x8 af[MI], bfv[4];
      #pragma unroll
      for (int mi = 0; mi < MI; ++mi) {
        const int row  = waveM * (BM / 2) + mi * 16 + l16;
        const int slot = (ks * 4 + quad) ^ xr;
        af[mi] = *(const s16x8*)&As[row * 64 + slot * 8];
      }
      #pragma unroll
      for (int ni = 0; ni < 4; ++ni) {
        const int row  = waveN * 64 + ni * 16 + l16;
        const int slot = (ks * 4 + quad) ^ xr;
        bfv[ni] = *(const s16x8*)&Bs[row * 64 + slot * 8];
      }
      #pragma unroll
      for (int mi = 0; mi < MI; ++mi)
        #pragma unroll
        for (int ni = 0; ni < 4; ++ni)
          acc[mi * 4 + ni] = __builtin_amdgcn_mfma_f32_16x16x32_bf16(
              af[mi], bfv[ni], acc[mi * 4 + ni], 0, 0, 0);
    }
    __syncthreads();
  }
}

// ---------- f32-A x bf16-B core for proj: BM=64, BN=256 ----------
// A f32 prefetched into registers one K-step ahead (T14 async-STAGE split);
// raw s_barrier + counted s_waitcnt vmcnt(4) keeps the 4 in-flight A loads
// alive across the barrier (a plain __syncthreads would drain vmcnt to 0 and
// defeat the prefetch). B bf16 on the async global_load_lds path.
// Wave tile 32x128. Numerically identical to the round-1 core.
template<int K, int LDA, int LDB>
__device__ __forceinline__ void gemm_core_f32a(const float* __restrict__ A,
                                               const bf16* __restrict__ Bw,
                                               int bm, int bn,
                                               short* As, short* Bs, f32x4* acc)
{
  const int tid  = threadIdx.x;
  const int lane = tid & 63;
  const int wave = tid >> 6;
  const int l8   = lane >> 3;
  const int kch  = ((lane & 7) ^ l8) * 8;
  const bf16* bg = Bw + (size_t)(bn * 256 + wave * 64 + l8) * LDB + kch;
  short* BsW = Bs + wave * 64 * 64;
  const int arow = tid >> 3;
  const int ag8  = tid & 7;
  const int slotA = (ag8 ^ (arow & 7)) * 8;
  const float* ag = A + (size_t)(bm * 64 + arow) * LDA + ag8 * 8;
  const int waveM = wave >> 1, waveN = wave & 1;
  const int l16  = lane & 15;
  const int quad = lane >> 4;
  const int xr   = l16 & 7;

  #pragma unroll
  for (int t = 0; t < 16; ++t)
    #pragma unroll
    for (int r = 0; r < 4; ++r) acc[t][r] = 0.0f;

  // prologue: A regs for kt=0
  float4 a0 = ((const float4*)ag)[0];
  float4 b0 = ((const float4*)ag)[1];
  float4 a1 = ((const float4*)(ag + (size_t)32 * LDA))[0];
  float4 b1 = ((const float4*)(ag + (size_t)32 * LDA))[1];
  ag += 64;

  for (int kt = 0; kt < K / 64; ++kt) {
    // (1) issue B DMA loads (must be the 8 oldest vm ops at the waitcnt)
    #pragma unroll
    for (int j = 0; j < 8; ++j) async_ld16(bg + (size_t)j * 8 * LDB, BsW + j * 8 * 64);
    bg += 64;
    __builtin_amdgcn_sched_barrier(0);
    // (2) cvt current A regs -> swizzled LDS (compiler waits on their loads)
    {
      u16x8 v;
      v[0] = f2bfu(a0.x); v[1] = f2bfu(a0.y); v[2] = f2bfu(a0.z); v[3] = f2bfu(a0.w);
      v[4] = f2bfu(b0.x); v[5] = f2bfu(b0.y); v[6] = f2bfu(b0.z); v[7] = f2bfu(b0.w);
      *(u16x8*)&As[arow * 64 + slotA] = v;
      v[0] = f2bfu(a1.x); v[1] = f2bfu(a1.y); v[2] = f2bfu(a1.z); v[3] = f2bfu(a1.w);
      v[4] = f2bfu(b1.x); v[5] = f2bfu(b1.y); v[6] = f2bfu(b1.z); v[7] = f2bfu(b1.w);
      *(u16x8*)&As[(32 + arow) * 64 + slotA] = v;
    }
    // (3) issue next-iteration A loads (stay in flight across the barrier);
    //     last iter re-reads the current chunk to keep vmcnt count constant
    //     and stay in-bounds.
    const float* agn = (kt == K / 64 - 1) ? (ag - 64) : ag;
    float4 na0 = ((const float4*)agn)[0];
    float4 nb0 = ((const float4*)agn)[1];
    float4 na1 = ((const float4*)(agn + (size_t)32 * LDA))[0];
    float4 nb1 = ((const float4*)(agn + (size_t)32 * LDA))[1];
    ag += 64;
    __builtin_amdgcn_sched_barrier(0);
    // B DMAs (8) done; A prefetch (4) may remain in flight; LDS writes done.
    asm volatile("s_waitcnt vmcnt(4) lgkmcnt(0)" ::: "memory");
    __builtin_amdgcn_s_barrier();
    __builtin_amdgcn_sched_barrier(0);
    #pragma unroll
    for (int ks = 0; ks < 2; ++ks) {
      s16x8 af[2], bfv[8];
      #pragma unroll
      for (int mi = 0; mi < 2; ++mi) {
        const int row  = waveM * 32 + mi * 16 + l16;
        const int slot = (ks * 4 + quad) ^ xr;
        af[mi] = *(const s16x8*)&As[row * 64 + slot * 8];
      }
      #pragma unroll
      for (int ni = 0; ni < 8; ++ni) {
        const int row  = waveN * 128 + ni * 16 + l16;
        const int slot = (ks * 4 + quad) ^ xr;
        bfv[ni] = *(const s16x8*)&Bs[row * 64 + slot * 8];
      }
      #pragma unroll
      for (int mi = 0; mi < 2; ++mi)
        #pragma unroll
        for (int ni = 0; ni < 8; ++ni)
          acc[mi * 8 + ni] = __builtin_amdgcn_mfma_f32_16x16x32_bf16(
              af[mi], bfv[ni], acc[mi * 8 + ni], 0, 0, 0);
    }
    __builtin_amdgcn_sched_barrier(0);
    asm volatile("s_waitcnt lgkmcnt(0)" ::: "memory");
    __builtin_amdgcn_s_barrier();
    __builtin_amdgcn_sched_barrier(0);
    a0 = na0; b0 = nb0; a1 = na1; b1 = nb1;
  }
}

// z=0: q = (Xq Wq^T + bq) * 512^-0.5 ; z=1: k = Xk Wk^T + bk ;
// z=2: vT[b][d][s] = (Xv Wv^T + bv)^T.
// Flat 768-block grid; the two bn-siblings of each (bm,z) panel get linear
// ids differing by 8 -> same XCD -> A panel shared in that XCD's L2.
__global__ __launch_bounds__(256, 3)
void proj_kernel(const float* __restrict__ Xq, const float* __restrict__ Xk,
                 const float* __restrict__ Xv, const bf16* __restrict__ W0,
                 const float* __restrict__ bq, const float* __restrict__ bk,
                 const float* __restrict__ bv,
                 bf16* __restrict__ qo, bf16* __restrict__ ko,
                 bf16* __restrict__ vT, float qscale)
{
  __shared__ __align__(16) short As[64 * 64];
  __shared__ __align__(16) short Bs[256 * 64];
  const int id   = blockIdx.x;
  const int xcd  = id & 7;
  const int s    = id >> 3;            // 0..95
  const int bn   = s & 1;
  const int pair = (s >> 1) * 8 + xcd; // 0..383 unique
  const int bm   = pair & 127;
  const int z    = pair >> 7;          // 0..2
  const float* A  = (z == 0) ? Xq : (z == 1) ? Xk : Xv;
  const bf16*  Bw = W0 + ((size_t)z << 19);
  const float* bias = (z == 0) ? bq : (z == 1) ? bk : bv;
  f32x4 acc[16];
  gemm_core_f32a<1024, 1024, 1024>(A, Bw, bm, bn, As, Bs, acc);

  const int lane = threadIdx.x & 63;
  const int wave = threadIdx.x >> 6;
  const int waveM = wave >> 1, waveN = wave & 1;
  const int l16 = lane & 15, quad = lane >> 4;
  const int row0 = bm * 64 + waveM * 32;
  const int col0 = bn * 256 + waveN * 128;
  const float sc = (z == 0) ? qscale : 1.0f;
  bf16* C = (z == 0) ? qo : ko;
  #pragma unroll
  for (int ni = 0; ni < 8; ++ni) {
    const int col = col0 + ni * 16 + l16;
    const float bb = bias[col];
    #pragma unroll
    for (int mi = 0; mi < 2; ++mi)
      #pragma unroll
      for (int r = 0; r < 4; ++r) {
        const int row = row0 + mi * 16 + quad * 4 + r;
        const float v = acc[mi * 8 + ni][r] + bb;
        if (z == 2)
          vT[((size_t)(row >> 10) * DKK + col) * SS + (row & (SS - 1))] =
              __float2bfloat16(v);
        else
          C[(size_t)row * DKK + col] = __float2bfloat16(v * sc);
      }
  }
}

// logits[b][s][t] = q[b][s].k[b][t]; 64x128 tiles, pure GEMM + store.
// Flat grid 1024 (4 blocks/CU): z = id&7 (head pinned to its XCD; q+k for
// one z = 2 MiB, L2-resident), s = id>>3: bm = s&15, bn = s>>4.
__global__ __launch_bounds__(256, 4)
void scores_kernel(const bf16* __restrict__ q, const bf16* __restrict__ k,
                   bf16* __restrict__ lgB)
{
  __shared__ __align__(16) short As[64 * 64];
  __shared__ __align__(16) short Bs[128 * 64];
  const int id = blockIdx.x;
  const int z  = id & 7;
  const int s  = id >> 3;          // 0..127
  const int bm = s & 15;
  const int bn = s >> 4;           // 0..7
  f32x4 acc[8];
  gemm_core<64, 512, 512, 512>(q + (size_t)z * SS * DKK, k + (size_t)z * SS * DKK,
                               bm, bn, As, Bs, acc);

  const int lane = threadIdx.x & 63;
  const int wave = threadIdx.x >> 6;
  const int waveM = wave >> 1, waveN = wave & 1;
  const int l16 = lane & 15, quad = lane >> 4;
  const int row0 = bm * 64 + waveM * 32;
  const int col0 = bn * 128 + waveN * 64;
  bf16* C = lgB + (size_t)z * SS * SS;
  #pragma unroll
  for (int ni = 0; ni < 4; ++ni) {
    const int col = col0 + ni * 16 + l16;
    #pragma unroll
    for (int mi = 0; mi < 2; ++mi)
      #pragma unroll
      for (int r = 0; r < 4; ++r) {
        const int row = row0 + mi * 16 + quad * 4 + r;
        C[(size_t)row * SS + col] = __float2bfloat16(acc[mi * 4 + ni][r]);
      }
  }
}

// In-place row softmax over the bf16 logits: P = exp(x - max) / sum.
// One wave per row (1024 cols = 16 bf16/lane). Flat grid 2048:
// z = id&7, rb = id>>3 (4 rows per block, one per wave).
__global__ __launch_bounds__(256)
void softmax_p(unsigned short* __restrict__ lg)
{
  const int id = blockIdx.x;
  const int z  = id & 7;
  const int rb = id >> 3;               // 0..255
  const int w    = threadIdx.x >> 6;
  const int lane = threadIdx.x & 63;
  const int row  = rb * 4 + w;
  unsigned short* p = lg + ((size_t)z * SS + row) * SS + lane * 16;

  u16x8 a = *(const u16x8*)p;
  u16x8 b = *(const u16x8*)(p + 8);
  float xf[16];
  #pragma unroll
  for (int j = 0; j < 8; ++j) { xf[j] = bfu2f(a[j]); xf[8 + j] = bfu2f(b[j]); }

  float m = xf[0];
  #pragma unroll
  for (int j = 1; j < 16; ++j) m = fmaxf(m, xf[j]);
  #pragma unroll
  for (int msk = 1; msk < 64; msk <<= 1) m = fmaxf(m, __shfl_xor(m, msk));

  float e[16];
  float L = 0.f;
  #pragma unroll
  for (int j = 0; j < 16; ++j) { e[j] = __expf(xf[j] - m); L += e[j]; }
  #pragma unroll
  for (int msk = 1; msk < 64; msk <<= 1) L += __shfl_xor(L, msk);
  const float R = 1.0f / L;

  u16x8 o0, o1;
  #pragma unroll
  for (int j = 0; j < 8; ++j) {
    o0[j] = f2bfu(e[j] * R);
    o1[j] = f2bfu(e[8 + j] * R);
  }
  *(u16x8*)p = o0;
  *(u16x8*)(p + 8) = o1;
}

// out[b][s][d] = P[b][s][:] . vT[b][d][:]; pure bf16 GEMM, f32 out.
// 64x128 tiles. Flat grid 512 (2 blocks/CU): z = id&7 (P slab 2 MiB + vT
// 1 MiB per z, L2-resident), s = id>>3: bm = s&15, bn = s>>4 (0..3).
__global__ __launch_bounds__(256, 4)
void pv_kernel(const bf16* __restrict__ P, const bf16* __restrict__ vT,
               float* __restrict__ out)
{
  __shared__ __align__(16) short As[64 * 64];
  __shared__ __align__(16) short Bs[128 * 64];
  const int id = blockIdx.x;
  const int z  = id & 7;
  const int s  = id >> 3;          // 0..63
  const int bm = s & 15;
  const int bn = s >> 4;           // 0..3
  f32x4 acc[8];
  gemm_core<64, 1024, 1024, 1024>(P + (size_t)z * SS * SS,
                                  vT + (size_t)z * DKK * SS,
                                  bm, bn, As, Bs, acc);

  const int lane = threadIdx.x & 63;
  const int wave = threadIdx.x >> 6;
  const int waveM = wave >> 1, waveN = wave & 1;
  const int l16 = lane & 15, quad = lane >> 4;
  const int row0 = bm * 64 + waveM * 32;
  const int col0 = bn * 128 + waveN * 64;
  float* C = out + (size_t)z * SS * DKK;
  #pragma unroll
  for (int ni = 0; ni < 4; ++ni) {
    const int col = col0 + ni * 16 + l16;
    #pragma unroll
    for (int mi = 0; mi < 2; ++mi)
      #pragma unroll
      for (int r = 0; r < 4; ++r) {
        const int row = row0 + mi * 16 + quad * 4 + r;
        C[(size_t)row * DKK + col] = acc[mi * 4 + ni][r];
      }
  }
}

extern "C" void kernel_launch(void* const* d_in, const int* in_sizes, int n_in,
                              void* d_out, int out_size, void* d_ws, size_t ws_size,
                              hipStream_t stream)
{
  char* ws = (char*)d_ws;
  bf16*  W0   = (bf16*)(ws + WS_W(0));
  bf16*  q    = (bf16*)(ws + WS_Q);
  bf16*  kk   = (bf16*)(ws + WS_K);
  bf16*  vT   = (bf16*)(ws + WS_VT);
  bf16*  lgB  = (bf16*)(ws + WS_LG);

  const float qscale = 0.044194173824159216f;  // 512^-0.5

  dim3 blk(256, 1, 1);
  // d_in order: qin,kin,vin,Wq,bq,Wk,bk,Wv,bv (all f32)
  hipLaunchKernelGGL(convert_w, dim3(768), blk, 0, stream,
                     (const float*)d_in[3], (const float*)d_in[5],
                     (const float*)d_in[7], ws);
  hipLaunchKernelGGL(proj_kernel, dim3(768, 1, 1), blk, 0, stream,
                     (const float*)d_in[0], (const float*)d_in[1],
                     (const float*)d_in[2], W0,
                     (const float*)d_in[4], (const float*)d_in[6],
                     (const float*)d_in[8], q, kk, vT, qscale);
  hipLaunchKernelGGL(scores_kernel, dim3(1024, 1, 1), blk, 0, stream,
                     q, kk, lgB);
  hipLaunchKernelGGL(softmax_p, dim3(2048, 1, 1), blk, 0, stream,
                     (unsigned short*)lgB);
  hipLaunchKernelGGL(pv_kernel, dim3(512, 1, 1), blk, 0, stream,
                     lgB, vT, (float*)d_out);
}